// Round 3
// baseline (382.222 us; speedup 1.0000x reference)
//
#include <hip/hip_runtime.h>
#include <hip/hip_cooperative_groups.h>
#include <stdint.h>

namespace cg = cooperative_groups;

#define NBOX 2000000
#define NCLS 10
#define KPRE 4096
#define KPOST 500
#define NSEG 64
#define SEGC 4096    // cand per-segment cap
#define PCAP 131072  // pair cap (single linear buffer)
#define LCAP 16384   // LDS pair cache (64 KB)
#define BCAP 8192    // LDS bucket cap (aliases lp)
#define CSTR 16      // counter stride in u32 (one 64B cacheline per counter)
#define NTILE ((NSEG * (NSEG + 1)) / 2)  // 2080 triangular tiles

// ---- workspace layout (bytes) ----
#define OFF_KEYS   ((size_t)0)                               // NBOX*4 (u32 ord; idx implicit)
#define OFF_CAND   ((size_t)8000000)
#define OFF_SEL    (OFF_CAND  + (size_t)NSEG * SEGC * 8)     // unused (kept for layout stability)
#define OFF_SKEYS  (OFF_SEL   + (size_t)NSEG * 1024 * 8)
#define OFF_PAIRS  (OFF_SKEYS + (size_t)KPRE * 8)            // PCAP u32 pairs
#define OFF_VMASK  (OFF_PAIRS + (size_t)PCAP * 4)
#define OFF_HIST   (OFF_VMASK + (size_t)64 * 8)
#define OFF_CNTS   (OFF_HIST  + (size_t)768 * 4)             // 3*64 counters, 64B stride
#define OFF_STATE  (OFF_CNTS  + (size_t)3 * NSEG * CSTR * 4)
#define OFF_ARR    (OFF_STATE + (size_t)64)
#define OFF_LAB    (OFF_ARR   + (size_t)KPRE * 24)           // NBOX u8 labels
#define ZERO_BYTES ((size_t)(64 * 8 + 768 * 4 + 3 * NSEG * CSTR * 4 + 64))  // vmask..state

__device__ __forceinline__ uint32_t f2ord(float f) {
  uint32_t b = __float_as_uint(f);
  return (b & 0x80000000u) ? ~b : (b | 0x80000000u);
}
__device__ __forceinline__ float ord2f(uint32_t ord) {
  uint32_t b = (ord & 0x80000000u) ? (ord ^ 0x80000000u) : ~ord;
  return __uint_as_float(b);
}

__device__ __forceinline__ unsigned long long shflx64(unsigned long long v, int mask) {
  union { unsigned long long u; int i[2]; } a; a.u = v;
  a.i[0] = __shfl_xor(a.i[0], mask, 64);
  a.i[1] = __shfl_xor(a.i[1], mask, 64);
  return a.u;
}

// executed by one FULL wave (lanes 0..63): bucket of the need-th smallest in h[256]
__device__ __forceinline__ void wave_bucket(const uint32_t* __restrict__ h, uint32_t need,
                                            uint32_t* bin_out, uint32_t* nd_out) {
  int l = threadIdx.x & 63;
  uint4 h4 = reinterpret_cast<const uint4*>(h)[l];
  uint32_t s = h4.x + h4.y + h4.z + h4.w;
  uint32_t p = s;
  #pragma unroll
  for (int d = 1; d < 64; d <<= 1) {
    uint32_t v = __shfl_up(p, d, 64);
    if (l >= d) p += v;
  }
  uint32_t e0 = p - s, e1 = e0 + h4.x, e2 = e1 + h4.y, e3 = e2 + h4.z, e4 = e3 + h4.w;
  uint32_t eb[5] = {e0, e1, e2, e3, e4};
  uint32_t bin = 0xFFFFFFFFu, nd = 1;
  #pragma unroll
  for (int q = 0; q < 4; ++q)
    if (eb[q] < need && need <= eb[q + 1]) { bin = (uint32_t)(4 * l + q); nd = need - eb[q]; }
  unsigned long long mm = __ballot(bin != 0xFFFFFFFFu);
  int src = mm ? __builtin_ctzll(mm) : 0;
  *bin_out = (uint32_t)__shfl((int)bin, src);
  *nd_out  = (uint32_t)__shfl((int)nd, src);
}

// wave-aggregated LDS histogram add — fast when bins are near-uniform within the wave
__device__ __forceinline__ void hist_add_wave(uint32_t* lh, uint32_t bin) {
  unsigned long long act = __ballot(1);
  int lane = threadIdx.x & 63;
  unsigned long long rem = act;
  while (rem) {
    int leader = __builtin_ctzll(rem);
    uint32_t lb = __shfl(bin, leader);
    unsigned long long same = __ballot(bin == lb) & act;
    if (lane == leader) atomicAdd(&lh[lb], (uint32_t)__builtin_popcountll(same));
    rem &= ~same;
  }
}

// wave-aggregated compaction (u64 payload): one atomic per wave; works with partial masks
__device__ __forceinline__ void wave_compact(bool take, unsigned long long key,
                                             uint32_t* counter, unsigned long long* buf,
                                             uint32_t cap) {
  unsigned long long mm = __ballot(take);
  if (take) {
    int lane = threadIdx.x & 63;
    unsigned long long lt = (lane == 0) ? 0ull : (~0ull >> (64 - lane));
    int rank = __builtin_popcountll(mm & lt);
    int leader = __builtin_ctzll(mm);
    uint32_t base = 0;
    if (rank == 0) base = atomicAdd(counter, (uint32_t)__builtin_popcountll(mm));
    base = __shfl(base, leader);
    uint32_t pos = base + (uint32_t)rank;
    if (pos < cap) buf[pos] = key;
  }
}

// wave-aggregated compaction (u32 payload)
__device__ __forceinline__ void wave_compact32(bool take, uint32_t key,
                                               uint32_t* counter, uint32_t* buf,
                                               uint32_t cap) {
  unsigned long long mm = __ballot(take);
  if (take) {
    int lane = threadIdx.x & 63;
    unsigned long long lt = (lane == 0) ? 0ull : (~0ull >> (64 - lane));
    int rank = __builtin_popcountll(mm & lt);
    int leader = __builtin_ctzll(mm);
    uint32_t base = 0;
    if (rank == 0) base = atomicAdd(counter, (uint32_t)__builtin_popcountll(mm));
    base = __shfl(base, leader);
    uint32_t pos = base + (uint32_t)rank;
    if (pos < cap) buf[pos] = key;
  }
}

// ---------------- kernels ----------------

// scores (max over classes) -> u32 ord keys + per-box argmax label + byte0 histogram
__global__ void k_score(const float* __restrict__ cls, uint32_t* __restrict__ keys,
                        uint8_t* __restrict__ labs, uint32_t* __restrict__ hist0) {
  __shared__ uint32_t lh[256];
  for (int i = threadIdx.x; i < 256; i += blockDim.x) lh[i] = 0;
  __syncthreads();
  const int nvec = NBOX / 4;
  for (int v = blockIdx.x * blockDim.x + threadIdx.x; v < nvec; v += gridDim.x * blockDim.x) {
    float4 m = reinterpret_cast<const float4*>(cls)[v];
    int lx = 0, ly = 0, lz = 0, lw = 0;
    #pragma unroll
    for (int c = 1; c < NCLS; ++c) {
      float4 x = reinterpret_cast<const float4*>(cls + (size_t)c * NBOX)[v];
      if (x.x > m.x) { m.x = x.x; lx = c; }
      if (x.y > m.y) { m.y = x.y; ly = c; }
      if (x.z > m.z) { m.z = x.z; lz = c; }
      if (x.w > m.w) { m.w = x.w; lw = c; }
    }
    float s[4] = {m.x, m.y, m.z, m.w};
    uint32_t u4[4];
    #pragma unroll
    for (int q = 0; q < 4; ++q) {
      float ms = (s[q] >= 0.1f) ? s[q] : -1.0f;
      uint32_t u = ~f2ord(ms);
      u4[q] = u;
      hist_add_wave(lh, u >> 24);   // bins near-constant (byte0) -> 1-2 iters
    }
    reinterpret_cast<uint4*>(keys)[v] = make_uint4(u4[0], u4[1], u4[2], u4[3]);
    uchar4 lb; lb.x = (uint8_t)lx; lb.y = (uint8_t)ly; lb.z = (uint8_t)lz; lb.w = (uint8_t)lw;
    reinterpret_cast<uchar4*>(labs)[v] = lb;
  }
  __syncthreads();
  for (int i = threadIdx.x; i < 256; i += blockDim.x)
    if (lh[i]) atomicAdd(&hist0[i], lh[i]);
}

// Everything after k_score in ONE cooperative kernel: 64 blocks x 1024 threads.
// P1 hist1 | sync | P2 compact+hist2 | sync | P3 bucket+pivot(redundant per block)+selgather
// | sync | P4 pairs | sync | P5 fix (block 0)
__global__ void __launch_bounds__(1024) k_mega(
    const uint32_t* __restrict__ keys,
    const uint32_t* __restrict__ hist0, uint32_t* __restrict__ hist1,
    uint32_t* __restrict__ hist2,
    unsigned long long* __restrict__ cand, uint32_t* __restrict__ cntc,
    const float* __restrict__ boxes, const uint8_t* __restrict__ labs,
    float* __restrict__ x1a, float* __restrict__ y1a,
    float* __restrict__ x2a, float* __restrict__ y2a,
    float* __restrict__ vala, int* __restrict__ laba,
    unsigned long long* __restrict__ skeys, unsigned long long* __restrict__ vmask,
    uint32_t* __restrict__ selcnt, uint32_t* __restrict__ paircnt,
    uint32_t* __restrict__ pairs, float* __restrict__ out) {
#pragma clang fp contract(off)
  cg::grid_group grid = cg::this_grid();

  __shared__ uint32_t lh[256];
  __shared__ uint32_t lp[LCAP];            // P3: aliased as u64 bucket ls[]; P5: pair cache
  __shared__ unsigned long long lk[KPRE];
  __shared__ float psx1[16][64], psy1[16][64], psx2[16][64], psy2[16][64], psar[16][64];
  __shared__ unsigned long long psk[16][64];
  __shared__ unsigned long long validm[64], accm[64];
  __shared__ uint32_t supp[128];
  __shared__ uint32_t hsel[256];
  __shared__ uint32_t lsel[512];
  __shared__ unsigned long long kkbuf[512];
  __shared__ uint32_t sb1, sp16, sp24, s_need, s_lcnt, chg, scnt2, sneed2;
  __shared__ unsigned long long s_piv, spre;
  __shared__ uint32_t orlo, orhi, andlo, andhi;

  int tid = threadIdx.x;
  int wid = tid >> 6, lane = tid & 63;
  int blk = blockIdx.x;

  // ---- P1: hist1 (byte1 | byte0 == b1) ----
  if (tid < 64) {
    uint32_t b1, nd1;
    wave_bucket(hist0, KPRE, &b1, &nd1);
    if (tid == 0) sb1 = b1;
  }
  for (int i = tid; i < 256; i += 1024) lh[i] = 0;
  __syncthreads();
  {
    uint32_t B1 = sb1;
    for (int i = blk * 1024 + tid; i < NBOX; i += NSEG * 1024) {
      uint32_t u = keys[i];
      if ((u >> 24) == B1) atomicAdd(&lh[(u >> 16) & 0xffu], 1u);
    }
  }
  __syncthreads();
  for (int i = tid; i < 256; i += 1024)
    if (lh[i]) atomicAdd(&hist1[i], lh[i]);
  __threadfence();
  grid.sync();

  // ---- P2: compact (top16 <= p16) into own segment + hist2 ----
  if (tid < 64) {
    uint32_t b1, nd1, b2, nd2;
    wave_bucket(hist0, KPRE, &b1, &nd1);
    wave_bucket(hist1, nd1, &b2, &nd2);
    if (tid == 0) sp16 = (b1 << 8) | b2;
  }
  for (int i = tid; i < 256; i += 1024) lh[i] = 0;
  __syncthreads();
  {
    uint32_t p16 = sp16;
    uint32_t* ctr = cntc + blk * CSTR;
    unsigned long long* buf = cand + (size_t)blk * SEGC;
    for (int i = blk * 1024 + tid; i < NBOX; i += NSEG * 1024) {
      uint32_t u = keys[i];
      uint32_t pref = u >> 16;
      bool take = (pref <= p16);
      unsigned long long key = ((unsigned long long)u << 32) | (uint32_t)i;
      wave_compact(take, key, ctr, buf, SEGC);
      if (take && pref == p16) atomicAdd(&lh[(u >> 8) & 0xffu], 1u);
    }
  }
  __syncthreads();
  for (int i = tid; i < 256; i += 1024)
    if (lh[i]) atomicAdd(&hist2[i], lh[i]);
  __threadfence();
  grid.sync();

  // ---- P3: bucket extract (all segments, L2-hot) + redundant per-block pivot + selgather ----
  {
    unsigned long long* ls = reinterpret_cast<unsigned long long*>(lp);  // 8192 u64 cap
    if (tid < 64) {
      uint32_t b1, nd1, b2, nd2, b3, nd3;
      wave_bucket(hist0, KPRE, &b1, &nd1);
      wave_bucket(hist1, nd1, &b2, &nd2);
      wave_bucket(hist2, nd2, &b3, &nd3);
      if (tid == 0) { sp24 = (b1 << 16) | (b2 << 8) | b3; s_need = nd3; s_lcnt = 0; }
    }
    __syncthreads();
    uint32_t p24 = sp24;
    // every block scans ALL segments (just-written, L2/L3-resident) into its own LDS
    for (int g = wid; g < NSEG; g += 16) {
      uint32_t n = min(cntc[g * CSTR], (uint32_t)SEGC);
      const unsigned long long* src = cand + (size_t)g * SEGC;
      for (uint32_t i = (uint32_t)lane; i < n; i += 64) {
        unsigned long long key = src[i];
        wave_compact((uint32_t)(key >> 40) == p24, key, &s_lcnt, ls, (uint32_t)BCAP);
      }
    }
    __syncthreads();
    uint32_t cnum = min(s_lcnt, (uint32_t)BCAP);
    uint32_t need = s_need;
    for (uint32_t e = (uint32_t)tid; e < cnum; e += 1024) {
      unsigned long long k0 = ls[e];
      uint32_t r = 0;
      for (uint32_t p = 0; p < cnum; ++p) r += (ls[p] < k0) ? 1u : 0u;
      if (r == need - 1) s_piv = k0;
    }
    __syncthreads();
    unsigned long long piv = s_piv;
    // selgather: block scans its OWN segment, writes final slots via one global counter
    uint32_t n = min(cntc[blk * CSTR], (uint32_t)SEGC);
    const unsigned long long* src = cand + (size_t)blk * SEGC;
    for (uint32_t i = (uint32_t)tid; i < n; i += 1024) {
      unsigned long long key = src[i];
      bool take = (key <= piv);
      unsigned long long mm = __ballot(take);
      if (take) {
        unsigned long long lt = (lane == 0) ? 0ull : (~0ull >> (64 - lane));
        int rank = __builtin_popcountll(mm & lt);
        int leader = __builtin_ctzll(mm);
        uint32_t base = 0;
        if (rank == 0) base = atomicAdd(selcnt, (uint32_t)__builtin_popcountll(mm));
        base = __shfl(base, leader);
        uint32_t pos = base + (uint32_t)rank;
        if (pos < (uint32_t)KPRE) {
          uint32_t idx = (uint32_t)key;
          if (idx >= NBOX) idx = 0;  // safety
          uint32_t u = (uint32_t)(key >> 32);
          float val = ord2f(~u);
          x1a[pos] = boxes[idx];
          y1a[pos] = boxes[(size_t)NBOX + idx];
          x2a[pos] = boxes[(size_t)2 * NBOX + idx];
          y2a[pos] = boxes[(size_t)3 * NBOX + idx];
          vala[pos] = val;
          laba[pos] = (int)labs[idx];
          skeys[pos] = key;
          if (val >= 0.1f) atomicOr(&vmask[pos >> 6], 1ull << (pos & 63));
        }
      }
    }
  }
  __threadfence();
  grid.sync();

  // ---- P4: suppression pairs — 2080 triangular 64x64 tiles over all 1024 waves ----
  {
    int W = blk * 16 + wid;
    for (int T = W; T < NTILE; T += NSEG * 16) {
      int by = (int)(64.5f - sqrtf(64.5f * 64.5f - 2.0f * (float)T));
      if (by < 0) by = 0;
      if (by > 63) by = 63;
      while (by > 0 && T < by * 64 - (by * (by - 1)) / 2) --by;
      while (T >= (by + 1) * 64 - ((by + 1) * by) / 2) ++by;
      int cum = by * 64 - (by * (by - 1)) / 2;
      int bx = by + (T - cum);
      int t = lane;
      int i = by * 64 + t;
      int j0 = bx * 64 + t;
      float cx1 = x1a[j0], cy1 = y1a[j0], cx2 = x2a[j0], cy2 = y2a[j0];
      psx1[wid][t] = cx1; psy1[wid][t] = cy1; psx2[wid][t] = cx2; psy2[wid][t] = cy2;
      psar[wid][t] = fmaxf(cx2 - cx1, 0.0f) * fmaxf(cy2 - cy1, 0.0f);
      psk[wid][t] = skeys[j0];
      float x1i = x1a[i], y1i = y1a[i], x2i = x2a[i], y2i = y2a[i];
      unsigned long long rk = skeys[i];
      float ari = fmaxf(x2i - x1i, 0.0f) * fmaxf(y2i - y1i, 0.0f);
      unsigned long long w = 0ull;
      #pragma unroll 8
      for (int jj = 0; jj < 64; ++jj) {
        int j = bx * 64 + jj;
        float iw = fmaxf(fminf(x2i, psx2[wid][jj]) - fmaxf(x1i, psx1[wid][jj]), 0.0f);
        float ih = fmaxf(fminf(y2i, psy2[wid][jj]) - fmaxf(y1i, psy1[wid][jj]), 0.0f);
        float inter = iw * ih;
        float den = ((ari + psar[wid][jj]) - inter) + 1e-8f;  // exact ref op order
        float iou = inter / den;
        if ((iou > 0.5f) && (j > i)) w |= (1ull << jj);
      }
      while (__ballot(w != 0ull)) {
        bool tk = (w != 0ull);
        uint32_t pr = 0;
        if (tk) {
          int b = __builtin_ctzll(w); w &= w - 1;
          int j = bx * 64 + b;
          bool i_sup = (rk < psk[wid][b]);  // smaller key suppresses
          pr = i_sup ? (((uint32_t)i << 16) | (uint32_t)j)
                     : (((uint32_t)j << 16) | (uint32_t)i);
        }
        wave_compact32(tk, pr, paircnt, pairs, (uint32_t)PCAP);
      }
    }
  }
  __threadfence();
  grid.sync();

  if (blk != 0) return;

  // ---- P5 (block 0): Jacobi fixpoint + top-KPOST radix narrowing + rank emit ----
  for (int t = tid; t < KPOST * 6; t += 1024) out[t] = 0.0f;
  if (tid < 512) kkbuf[tid] = ~0ull;
  if (tid < 64) { validm[tid] = vmask[tid]; accm[tid] = vmask[tid]; }
  for (int t = tid; t < KPRE; t += 1024) lk[t] = skeys[t];
  uint32_t npair = *paircnt; if (npair > (uint32_t)PCAP) npair = (uint32_t)PCAP;
  bool uselds = (npair <= (uint32_t)LCAP);
  if (uselds) for (uint32_t p = (uint32_t)tid; p < npair; p += 1024) lp[p] = pairs[p];
  __syncthreads();

  while (true) {
    __syncthreads();
    if (tid < 128) supp[tid] = 0;
    if (tid == 0) chg = 0;
    __syncthreads();
    if (uselds) {
      for (uint32_t p = (uint32_t)tid; p < npair; p += 1024) {
        uint32_t pr = lp[p];
        uint32_t i = pr >> 16, j = pr & 0xffffu;
        if ((accm[i >> 6] >> (i & 63)) & 1ull) atomicOr(&supp[j >> 5], 1u << (j & 31));
      }
    } else {
      for (uint32_t p = (uint32_t)tid; p < npair; p += 1024) {
        uint32_t pr = pairs[p];
        uint32_t i = pr >> 16, j = pr & 0xffffu;
        if ((accm[i >> 6] >> (i & 63)) & 1ull) atomicOr(&supp[j >> 5], 1u << (j & 31));
      }
    }
    __syncthreads();
    if (tid < 64) {
      unsigned long long s = ((unsigned long long)supp[2 * tid + 1] << 32) | supp[2 * tid];
      unsigned long long na = validm[tid] & ~s;
      if (na != accm[tid]) { accm[tid] = na; atomicOr(&chg, 1u); }
    }
    __syncthreads();
    if (chg == 0) break;
  }

  // ---- top-KPOST of survivors by key (diff-guided radix narrowing) ----
  if (tid == 0) {
    uint32_t ns = 0;
    for (int l = 0; l < 64; ++l) ns += (uint32_t)__builtin_popcountll(accm[l]);
    sneed2 = (ns < (uint32_t)KPOST) ? ns : (uint32_t)KPOST;
    orlo = 0; orhi = 0; andlo = ~0u; andhi = ~0u; scnt2 = 0;
  }
  __syncthreads();
  uint32_t need0 = sneed2;
  if (need0 == 0) return;

  {
    unsigned long long myor = 0ull, myand = ~0ull;
    for (int t = tid; t < KPRE; t += 1024) {
      if ((accm[t >> 6] >> (t & 63)) & 1ull) {
        unsigned long long k = lk[t];
        myor |= k; myand &= k;
      }
    }
    #pragma unroll
    for (int d = 1; d < 64; d <<= 1) {
      myor |= shflx64(myor, d);
      myand &= shflx64(myand, d);
    }
    if (lane == 0) {
      atomicOr(&orlo, (uint32_t)myor); atomicOr(&orhi, (uint32_t)(myor >> 32));
      atomicAnd(&andlo, (uint32_t)myand); atomicAnd(&andhi, (uint32_t)(myand >> 32));
    }
  }
  __syncthreads();
  unsigned long long vor = ((unsigned long long)orhi << 32) | orlo;
  unsigned long long vand = ((unsigned long long)andhi << 32) | andlo;
  unsigned long long diff = vor ^ vand;
  unsigned long long pre = 0;
  uint32_t need = need0;
  for (int b = 7; b >= 0; --b) {
    uint32_t db = (uint32_t)(diff >> (8 * b)) & 255u;
    if (db == 0) { pre = (pre << 8) | ((uint32_t)(vand >> (8 * b)) & 255u); continue; }
    if (tid < 256) hsel[tid] = 0;
    __syncthreads();
    for (int t = tid; t < KPRE; t += 1024) {
      if ((accm[t >> 6] >> (t & 63)) & 1ull) {
        unsigned long long k = lk[t];
        bool pm = (b == 7) ? true : ((k >> (8 * b + 8)) == pre);
        if (pm) atomicAdd(&hsel[(uint32_t)(k >> (8 * b)) & 255u], 1u);
      }
    }
    __syncthreads();
    if (tid < 64) {
      uint32_t c0 = hsel[4 * tid], c1 = hsel[4 * tid + 1],
               c2 = hsel[4 * tid + 2], c3 = hsel[4 * tid + 3];
      uint32_t s = c0 + c1 + c2 + c3;
      uint32_t p = s;
      #pragma unroll
      for (int d = 1; d < 64; d <<= 1) {
        uint32_t v = __shfl_up(p, d, 64);
        if (tid >= d) p += v;
      }
      uint32_t e0 = p - s, e1 = e0 + c0, e2 = e1 + c1, e3 = e2 + c2, e4 = e3 + c3;
      uint32_t eb[5] = {e0, e1, e2, e3, e4};
      #pragma unroll
      for (int q = 0; q < 4; ++q) {
        if (eb[q] < need && need <= eb[q + 1]) {
          spre = (pre << 8) | (uint32_t)(4 * tid + q);
          sneed2 = need - eb[q];
        }
      }
    }
    __syncthreads();
    pre = spre; need = sneed2;
    __syncthreads();
  }
  unsigned long long T = pre;  // exact key of the need0-th smallest survivor

  for (int t = tid; t < KPRE; t += 1024) {
    bool take = ((accm[t >> 6] >> (t & 63)) & 1ull) && (lk[t] <= T);
    wave_compact32(take, (uint32_t)t, &scnt2, lsel, 512u);
  }
  __syncthreads();
  uint32_t cnt = min(scnt2, 512u);
  if (tid < (int)cnt) kkbuf[tid] = lk[lsel[tid]];
  __syncthreads();
  if (tid < (int)cnt) {
    unsigned long long k0 = kkbuf[tid];
    uint32_t rank = 0;
    #pragma unroll 8
    for (uint32_t p = 0; p < 512u; ++p) rank += (kkbuf[p] < k0) ? 1u : 0u;  // padded ~0ull
    if (rank < (uint32_t)KPOST) {
      int i = (int)lsel[tid];
      out[rank * 6 + 0] = x1a[i];
      out[rank * 6 + 1] = y1a[i];
      out[rank * 6 + 2] = x2a[i];
      out[rank * 6 + 3] = y2a[i];
      out[rank * 6 + 4] = vala[i];
      out[rank * 6 + 5] = (float)laba[i];
    }
  }
}

extern "C" void kernel_launch(void* const* d_in, const int* in_sizes, int n_in,
                              void* d_out, int out_size, void* d_ws, size_t ws_size,
                              hipStream_t stream) {
  const float* boxes = (const float*)d_in[0];
  const float* cls   = (const float*)d_in[1];
  float* out = (float*)d_out;
  char* ws = (char*)d_ws;

  uint32_t* keys = (uint32_t*)(ws + OFF_KEYS);
  unsigned long long* cand  = (unsigned long long*)(ws + OFF_CAND);
  unsigned long long* skeys = (unsigned long long*)(ws + OFF_SKEYS);
  uint32_t* pairs = (uint32_t*)(ws + OFF_PAIRS);
  unsigned long long* vmask = (unsigned long long*)(ws + OFF_VMASK);
  uint32_t* hist = (uint32_t*)(ws + OFF_HIST);
  uint32_t* cnts = (uint32_t*)(ws + OFF_CNTS);
  uint32_t* cntc  = cnts;                    // cand counters
  uint32_t* selcnt  = (uint32_t*)(ws + OFF_STATE + 8);
  uint32_t* paircnt = (uint32_t*)(ws + OFF_STATE + 16);
  float* x1a = (float*)(ws + OFF_ARR);
  float* y1a = x1a + KPRE;
  float* x2a = y1a + KPRE;
  float* y2a = x2a + KPRE;
  float* vala = y2a + KPRE;
  int*   laba = (int*)(vala + KPRE);
  uint8_t* labs = (uint8_t*)(ws + OFF_LAB);
  const uint32_t* hist0p = hist;
  uint32_t* hist1p = hist + 256;
  uint32_t* hist2p = hist + 512;
  const uint32_t* keysc = keys;

  // zero vmask+hist+cnts+state in one async memset (contiguous region)
  hipMemsetAsync(ws + OFF_VMASK, 0, ZERO_BYTES, stream);
  k_score<<<1024, 256, 0, stream>>>(cls, keys, labs, hist);
  void* args[] = {
    (void*)&keysc, (void*)&hist0p, (void*)&hist1p, (void*)&hist2p,
    (void*)&cand, (void*)&cntc, (void*)&boxes, (void*)&labs,
    (void*)&x1a, (void*)&y1a, (void*)&x2a, (void*)&y2a,
    (void*)&vala, (void*)&laba, (void*)&skeys, (void*)&vmask,
    (void*)&selcnt, (void*)&paircnt, (void*)&pairs, (void*)&out
  };
  hipLaunchCooperativeKernel((const void*)k_mega, dim3(NSEG), dim3(1024), args, 0, stream);
}

// Round 4
// 355.776 us; speedup vs baseline: 1.0743x; 1.0743x over previous
//
#include <hip/hip_runtime.h>
#include <stdint.h>

#define NBOX 2000000
#define NCLS 10
#define KPRE 4096
#define KPOST 500
#define NBLK 256
#define NTHR 1024
#define NWAV (NTHR / 64)
#define SEGC 2048        // cand per-segment cap (avg ~300/segment)
#define GCAP 6144        // gathered candidate cap (>= 4096 + p24-bucket size)
#define NMW  (GCAP / 64) // 96 mask words
#define PCAP 131072      // pair cap
#define CSTR 16          // counter stride in u32 (one 64B line per counter)

// ---- workspace layout (bytes) ----
#define OFF_KEYS  ((size_t)0)                              // NBOX*4
#define OFF_CAND  ((size_t)8000000)                        // NBLK*SEGC*8 = 4 MB
#define OFF_PAIRS (OFF_CAND + (size_t)NBLK * SEGC * 8)     // PCAP*4
#define OFF_ARR   (OFF_PAIRS + (size_t)PCAP * 4)           // 5 f32 + i32 + u64 per slot = 32 B * GCAP
#define OFF_LAB   (OFF_ARR + (size_t)GCAP * 32)            // NBOX u8
#define OFF_ZERO  (OFF_LAB + (size_t)NBOX)                 // hist(768*4) + cnts + state
#define ZERO_BYTES ((size_t)(768 * 4 + NBLK * CSTR * 4 + 64))

__device__ __forceinline__ uint32_t f2ord(float f) {
  uint32_t b = __float_as_uint(f);
  return (b & 0x80000000u) ? ~b : (b | 0x80000000u);
}
__device__ __forceinline__ float ord2f(uint32_t ord) {
  uint32_t b = (ord & 0x80000000u) ? (ord ^ 0x80000000u) : ~ord;
  return __uint_as_float(b);
}

__device__ __forceinline__ unsigned long long shflx64(unsigned long long v, int mask) {
  union { unsigned long long u; int i[2]; } a; a.u = v;
  a.i[0] = __shfl_xor(a.i[0], mask, 64);
  a.i[1] = __shfl_xor(a.i[1], mask, 64);
  return a.u;
}

// lean grid barrier: agent-scope counter + spin; tid0-only L2 flush/inv via __threadfence
__device__ __forceinline__ void gbar(uint32_t* bar, uint32_t target) {
  __syncthreads();  // drains vmcnt for all block writes
  if (threadIdx.x == 0) {
    __threadfence();  // release: writeback L2
    __hip_atomic_fetch_add(bar, 1u, __ATOMIC_RELEASE, __HIP_MEMORY_SCOPE_AGENT);
    while (__hip_atomic_load(bar, __ATOMIC_ACQUIRE, __HIP_MEMORY_SCOPE_AGENT) < target)
      __builtin_amdgcn_s_sleep(2);
    __threadfence();  // acquire: invalidate stale L1/L2 lines
  }
  __syncthreads();
}

// full-wave (lanes 0..63): bucket of the need-th smallest in h[256]
__device__ __forceinline__ void wave_bucket(const uint32_t* __restrict__ h, uint32_t need,
                                            uint32_t* bin_out, uint32_t* nd_out) {
  int l = threadIdx.x & 63;
  uint4 h4 = reinterpret_cast<const uint4*>(h)[l];
  uint32_t s = h4.x + h4.y + h4.z + h4.w;
  uint32_t p = s;
  #pragma unroll
  for (int d = 1; d < 64; d <<= 1) {
    uint32_t v = __shfl_up(p, d, 64);
    if (l >= d) p += v;
  }
  uint32_t e0 = p - s, e1 = e0 + h4.x, e2 = e1 + h4.y, e3 = e2 + h4.z, e4 = e3 + h4.w;
  uint32_t eb[5] = {e0, e1, e2, e3, e4};
  uint32_t bin = 0xFFFFFFFFu, nd = 1;
  #pragma unroll
  for (int q = 0; q < 4; ++q)
    if (eb[q] < need && need <= eb[q + 1]) { bin = (uint32_t)(4 * l + q); nd = need - eb[q]; }
  unsigned long long mm = __ballot(bin != 0xFFFFFFFFu);
  int src = mm ? __builtin_ctzll(mm) : 0;
  *bin_out = (uint32_t)__shfl((int)bin, src);
  *nd_out  = (uint32_t)__shfl((int)nd, src);
}

__device__ __forceinline__ void hist_add_wave(uint32_t* lh, uint32_t bin) {
  unsigned long long act = __ballot(1);
  int lane = threadIdx.x & 63;
  unsigned long long rem = act;
  while (rem) {
    int leader = __builtin_ctzll(rem);
    uint32_t lb = __shfl(bin, leader);
    unsigned long long same = __ballot(bin == lb) & act;
    if (lane == leader) atomicAdd(&lh[lb], (uint32_t)__builtin_popcountll(same));
    rem &= ~same;
  }
}

__device__ __forceinline__ void wave_compact(bool take, unsigned long long key,
                                             uint32_t* counter, unsigned long long* buf,
                                             uint32_t cap) {
  unsigned long long mm = __ballot(take);
  if (take) {
    int lane = threadIdx.x & 63;
    unsigned long long lt = (lane == 0) ? 0ull : (~0ull >> (64 - lane));
    int rank = __builtin_popcountll(mm & lt);
    int leader = __builtin_ctzll(mm);
    uint32_t base = 0;
    if (rank == 0) base = atomicAdd(counter, (uint32_t)__builtin_popcountll(mm));
    base = __shfl(base, leader);
    uint32_t pos = base + (uint32_t)rank;
    if (pos < cap) buf[pos] = key;
  }
}

__device__ __forceinline__ void wave_compact32(bool take, uint32_t key,
                                               uint32_t* counter, uint32_t* buf,
                                               uint32_t cap) {
  unsigned long long mm = __ballot(take);
  if (take) {
    int lane = threadIdx.x & 63;
    unsigned long long lt = (lane == 0) ? 0ull : (~0ull >> (64 - lane));
    int rank = __builtin_popcountll(mm & lt);
    int leader = __builtin_ctzll(mm);
    uint32_t base = 0;
    if (rank == 0) base = atomicAdd(counter, (uint32_t)__builtin_popcountll(mm));
    base = __shfl(base, leader);
    uint32_t pos = base + (uint32_t)rank;
    if (pos < cap) buf[pos] = key;
  }
}

// ONE kernel: A score | B hist1 | C compact+hist2+sentinels | D p24+selgather |
// E pairs | F fix(block 0). Lean agent-scope barriers between phases.
__global__ void __launch_bounds__(NTHR) k_all(
    const float* __restrict__ boxes, const float* __restrict__ cls,
    uint32_t* __restrict__ keys, uint8_t* __restrict__ labs,
    unsigned long long* __restrict__ cand, uint32_t* __restrict__ cntc,
    uint32_t* __restrict__ hist, uint32_t* __restrict__ state,
    float* __restrict__ x1a, float* __restrict__ y1a,
    float* __restrict__ x2a, float* __restrict__ y2a,
    float* __restrict__ vala, int* __restrict__ laba,
    unsigned long long* __restrict__ skg, uint32_t* __restrict__ pairs,
    float* __restrict__ out) {
#pragma clang fp contract(off)
  __shared__ unsigned long long lk[GCAP];        // D: select list | E: tile staging | F: key cache
  __shared__ unsigned long long validm[NMW], accm[NMW];
  __shared__ uint32_t lh[256];
  __shared__ uint32_t supp[NMW * 2];
  __shared__ uint32_t hsel[256];
  __shared__ uint32_t lsel[512];
  __shared__ unsigned long long kkbuf[512];
  __shared__ uint32_t sb1, sp16, sp24, dcnt, dbase, chg, scnt2, sneedS;
  __shared__ unsigned long long spre;
  __shared__ uint32_t orlo, orhi, andlo, andhi;

  int tid = threadIdx.x, blk = blockIdx.x;
  int wid = tid >> 6, lane = tid & 63;
  int gtid = blk * NTHR + tid;
  uint32_t* hist0 = hist;
  uint32_t* hist1 = hist + 256;
  uint32_t* hist2 = hist + 512;
  uint32_t* selcnt = state;
  uint32_t* paircnt = state + 1;
  uint32_t* bar = state + 2;
  const int nvec = NBOX / 4;

  // ---- A: score (max over classes) -> ord keys + labels + byte0 hist ----
  for (int i = tid; i < 256; i += NTHR) lh[i] = 0;
  __syncthreads();
  for (int v = gtid; v < nvec; v += NBLK * NTHR) {
    float4 m = reinterpret_cast<const float4*>(cls)[v];
    int lx = 0, ly = 0, lz = 0, lw = 0;
    #pragma unroll
    for (int c = 1; c < NCLS; ++c) {
      float4 x = reinterpret_cast<const float4*>(cls + (size_t)c * NBOX)[v];
      if (x.x > m.x) { m.x = x.x; lx = c; }
      if (x.y > m.y) { m.y = x.y; ly = c; }
      if (x.z > m.z) { m.z = x.z; lz = c; }
      if (x.w > m.w) { m.w = x.w; lw = c; }
    }
    float s[4] = {m.x, m.y, m.z, m.w};
    uint32_t u4[4];
    #pragma unroll
    for (int q = 0; q < 4; ++q) {
      float ms = (s[q] >= 0.1f) ? s[q] : -1.0f;
      uint32_t u = ~f2ord(ms);
      u4[q] = u;
      hist_add_wave(lh, u >> 24);
    }
    reinterpret_cast<uint4*>(keys)[v] = make_uint4(u4[0], u4[1], u4[2], u4[3]);
    uchar4 lb; lb.x = (uint8_t)lx; lb.y = (uint8_t)ly; lb.z = (uint8_t)lz; lb.w = (uint8_t)lw;
    reinterpret_cast<uchar4*>(labs)[v] = lb;
  }
  __syncthreads();
  for (int i = tid; i < 256; i += NTHR) if (lh[i]) atomicAdd(&hist0[i], lh[i]);
  gbar(&bar[0], NBLK);

  // ---- B: hist1 (byte1 | byte0 == b1) ----
  if (tid < 64) {
    uint32_t b1, nd1;
    wave_bucket(hist0, KPRE, &b1, &nd1);
    if (tid == 0) sb1 = b1;
  }
  for (int i = tid; i < 256; i += NTHR) lh[i] = 0;
  __syncthreads();
  {
    uint32_t B1 = sb1;
    for (int v = gtid; v < nvec; v += NBLK * NTHR) {
      uint4 kv = reinterpret_cast<const uint4*>(keys)[v];
      if ((kv.x >> 24) == B1) atomicAdd(&lh[(kv.x >> 16) & 255u], 1u);
      if ((kv.y >> 24) == B1) atomicAdd(&lh[(kv.y >> 16) & 255u], 1u);
      if ((kv.z >> 24) == B1) atomicAdd(&lh[(kv.z >> 16) & 255u], 1u);
      if ((kv.w >> 24) == B1) atomicAdd(&lh[(kv.w >> 16) & 255u], 1u);
    }
  }
  __syncthreads();
  for (int i = tid; i < 256; i += NTHR) if (lh[i]) atomicAdd(&hist1[i], lh[i]);
  gbar(&bar[1], NBLK);

  // ---- C: compact own stripe (top16 <= p16) into own segment + hist2 + sentinels ----
  if (tid < 64) {
    uint32_t b1, nd1, b2, nd2;
    wave_bucket(hist0, KPRE, &b1, &nd1);
    wave_bucket(hist1, nd1, &b2, &nd2);
    if (tid == 0) sp16 = (b1 << 8) | b2;
  }
  for (int i = tid; i < 256; i += NTHR) lh[i] = 0;
  __syncthreads();
  {
    uint32_t p16 = sp16;
    uint32_t* ctr = cntc + blk * CSTR;
    unsigned long long* buf = cand + (size_t)blk * SEGC;
    for (int v = gtid; v < nvec; v += NBLK * NTHR) {
      uint4 kv = reinterpret_cast<const uint4*>(keys)[v];
      uint32_t us[4] = {kv.x, kv.y, kv.z, kv.w};
      #pragma unroll
      for (int q = 0; q < 4; ++q) {
        uint32_t u = us[q];
        uint32_t pref = u >> 16;
        bool take = (pref <= p16);
        unsigned long long key = ((unsigned long long)u << 32) | (uint32_t)(4 * v + q);
        wave_compact(take, key, ctr, buf, SEGC);
        if (take && pref == p16) atomicAdd(&lh[(u >> 8) & 255u], 1u);
      }
    }
    // sentinel-pad gather arrays (D overwrites live slots; barrier separates)
    for (int t = gtid; t < GCAP; t += NBLK * NTHR) {
      x1a[t] = 0.0f; y1a[t] = 0.0f; x2a[t] = 0.0f; y2a[t] = 0.0f;
      vala[t] = -1.0f; laba[t] = 0; skg[t] = ~0ull;
    }
  }
  __syncthreads();
  for (int i = tid; i < 256; i += NTHR) if (lh[i]) atomicAdd(&hist2[i], lh[i]);
  gbar(&bar[2], NBLK);

  // ---- D: p24 + conservative select (whole p24 bucket) + contiguous gather ----
  if (tid < 64) {
    uint32_t b1, nd1, b2, nd2, b3, nd3;
    wave_bucket(hist0, KPRE, &b1, &nd1);
    wave_bucket(hist1, nd1, &b2, &nd2);
    wave_bucket(hist2, nd2, &b3, &nd3);
    if (tid == 0) { sp24 = (b1 << 16) | (b2 << 8) | b3; dcnt = 0; }
  }
  __syncthreads();
  {
    uint32_t p24 = sp24;
    uint32_t n = __hip_atomic_load(cntc + blk * CSTR, __ATOMIC_RELAXED, __HIP_MEMORY_SCOPE_AGENT);
    if (n > SEGC) n = SEGC;
    const unsigned long long* src = cand + (size_t)blk * SEGC;
    unsigned long long* dls = lk;  // LDS reuse as select list
    for (uint32_t i = (uint32_t)tid; i < n; i += NTHR) {
      unsigned long long key = src[i];
      wave_compact((uint32_t)(key >> 40) <= p24, key, &dcnt, dls, (uint32_t)GCAP);
    }
    __syncthreads();
    if (tid == 0) {
      uint32_t c = dcnt; if (c > GCAP) c = GCAP;
      dbase = __hip_atomic_fetch_add(selcnt, c, __ATOMIC_RELAXED, __HIP_MEMORY_SCOPE_AGENT);
      dcnt = c;
    }
    __syncthreads();
    uint32_t c = dcnt, base = dbase;
    for (uint32_t i = (uint32_t)tid; i < c; i += NTHR) {
      unsigned long long key = dls[i];
      uint32_t pos = base + i;
      if (pos < (uint32_t)GCAP) {
        uint32_t idx = (uint32_t)key; if (idx >= NBOX) idx = 0;
        uint32_t u = (uint32_t)(key >> 32);
        x1a[pos] = boxes[idx];
        y1a[pos] = boxes[(size_t)NBOX + idx];
        x2a[pos] = boxes[(size_t)2 * NBOX + idx];
        y2a[pos] = boxes[(size_t)3 * NBOX + idx];
        vala[pos] = ord2f(~u);
        laba[pos] = (int)labs[idx];
        skg[pos] = key;
      }
    }
  }
  gbar(&bar[3], NBLK);

  // ---- E: suppression pairs over dynamic triangular 64x64 tiles ----
  {
    uint32_t gc = __hip_atomic_load(selcnt, __ATOMIC_RELAXED, __HIP_MEMORY_SCOPE_AGENT);
    if (gc > (uint32_t)GCAP) gc = (uint32_t)GCAP;
    int rows = (int)((gc + 63) >> 6);
    int NT = rows * (rows + 1) / 2;
    float* psx1 = (float*)lk;  // staging carved from lk region (28 KB < 48 KB)
    float* psy1 = psx1 + NWAV * 64;
    float* psx2 = psy1 + NWAV * 64;
    float* psy2 = psx2 + NWAV * 64;
    float* psar = psy2 + NWAV * 64;
    unsigned long long* psk = (unsigned long long*)(psar + NWAV * 64);
    int W = blk * NWAV + wid;
    int wb = wid << 6;
    for (int T = W; T < NT; T += NBLK * NWAV) {
      float Rf = (float)rows;
      float disc = (2.0f * Rf + 1.0f) * (2.0f * Rf + 1.0f) - 8.0f * (float)T;
      disc = disc > 0.0f ? disc : 0.0f;
      int by = (int)(((2.0f * Rf + 1.0f) - sqrtf(disc)) * 0.5f);
      if (by < 0) by = 0;
      if (by > rows - 1) by = rows - 1;
      while (by > 0 && T < by * rows - (by * (by - 1)) / 2) --by;
      while (by < rows - 1 && T >= (by + 1) * rows - ((by + 1) * by) / 2) ++by;
      int cum = by * rows - (by * (by - 1)) / 2;
      int bx = by + (T - cum);
      int i = by * 64 + lane;
      int j0 = bx * 64 + lane;
      float cx1 = x1a[j0], cy1 = y1a[j0], cx2 = x2a[j0], cy2 = y2a[j0];
      psx1[wb + lane] = cx1; psy1[wb + lane] = cy1;
      psx2[wb + lane] = cx2; psy2[wb + lane] = cy2;
      psar[wb + lane] = fmaxf(cx2 - cx1, 0.0f) * fmaxf(cy2 - cy1, 0.0f);
      psk[wb + lane] = skg[j0];
      float x1i = x1a[i], y1i = y1a[i], x2i = x2a[i], y2i = y2a[i];
      unsigned long long rk = skg[i];
      float ari = fmaxf(x2i - x1i, 0.0f) * fmaxf(y2i - y1i, 0.0f);
      unsigned long long w = 0ull;
      #pragma unroll 8
      for (int jj = 0; jj < 64; ++jj) {
        int j = bx * 64 + jj;
        float iw = fmaxf(fminf(x2i, psx2[wb + jj]) - fmaxf(x1i, psx1[wb + jj]), 0.0f);
        float ih = fmaxf(fminf(y2i, psy2[wb + jj]) - fmaxf(y1i, psy1[wb + jj]), 0.0f);
        float inter = iw * ih;
        float den = ((ari + psar[wb + jj]) - inter) + 1e-8f;  // exact ref op order
        float iou = inter / den;
        if ((iou > 0.5f) && (j > i)) w |= (1ull << jj);
      }
      while (__ballot(w != 0ull)) {
        bool tk = (w != 0ull);
        uint32_t pr = 0;
        if (tk) {
          int b = __builtin_ctzll(w); w &= w - 1;
          int j = bx * 64 + b;
          bool i_sup = (rk < psk[wb + b]);  // smaller key suppresses
          pr = i_sup ? (((uint32_t)i << 16) | (uint32_t)j)
                     : (((uint32_t)j << 16) | (uint32_t)i);
        }
        wave_compact32(tk, pr, paircnt, pairs, (uint32_t)PCAP);
      }
    }
  }
  gbar(&bar[4], NBLK);
  if (blk != 0) return;

  // ---- F (block 0): exact top-4096 cut + Jacobi fixpoint + top-500 emit ----
  uint32_t gc = __hip_atomic_load(selcnt, __ATOMIC_RELAXED, __HIP_MEMORY_SCOPE_AGENT);
  if (gc > (uint32_t)GCAP) gc = (uint32_t)GCAP;
  uint32_t np = __hip_atomic_load(paircnt, __ATOMIC_RELAXED, __HIP_MEMORY_SCOPE_AGENT);
  if (np > (uint32_t)PCAP) np = (uint32_t)PCAP;
  for (int t = tid; t < KPOST * 6; t += NTHR) out[t] = 0.0f;
  if (tid < 512) kkbuf[tid] = ~0ull;
  for (int t = tid; t < GCAP; t += NTHR) lk[t] = (t < (int)gc) ? skg[t] : ~0ull;
  if (tid == 0) { orlo = 0; orhi = 0; andlo = ~0u; andhi = ~0u; scnt2 = 0; }
  __syncthreads();

  // radix #1: T1 = exact need1-th smallest key among gathered
  uint32_t need1 = (gc < (uint32_t)KPRE) ? gc : (uint32_t)KPRE;
  if (need1 == 0) return;
  {
    unsigned long long myor = 0ull, myand = ~0ull;
    for (int t = tid; t < (int)gc; t += NTHR) {
      unsigned long long k = lk[t];
      myor |= k; myand &= k;
    }
    #pragma unroll
    for (int d = 1; d < 64; d <<= 1) { myor |= shflx64(myor, d); myand &= shflx64(myand, d); }
    if (lane == 0) {
      atomicOr(&orlo, (uint32_t)myor); atomicOr(&orhi, (uint32_t)(myor >> 32));
      atomicAnd(&andlo, (uint32_t)myand); atomicAnd(&andhi, (uint32_t)(myand >> 32));
    }
  }
  __syncthreads();
  unsigned long long T1;
  {
    unsigned long long vor = ((unsigned long long)orhi << 32) | orlo;
    unsigned long long vand = ((unsigned long long)andhi << 32) | andlo;
    unsigned long long diff = vor ^ vand;
    unsigned long long pre = 0;
    uint32_t need = need1;
    for (int b = 7; b >= 0; --b) {
      uint32_t db = (uint32_t)(diff >> (8 * b)) & 255u;
      if (db == 0) { pre = (pre << 8) | ((uint32_t)(vand >> (8 * b)) & 255u); continue; }
      if (tid < 256) hsel[tid] = 0;
      __syncthreads();
      for (int t = tid; t < (int)gc; t += NTHR) {
        unsigned long long k = lk[t];
        bool pm = (b == 7) ? true : ((k >> (8 * b + 8)) == pre);
        if (pm) atomicAdd(&hsel[(uint32_t)(k >> (8 * b)) & 255u], 1u);
      }
      __syncthreads();
      if (tid < 64) {
        uint32_t c0 = hsel[4 * tid], c1 = hsel[4 * tid + 1],
                 c2 = hsel[4 * tid + 2], c3 = hsel[4 * tid + 3];
        uint32_t s = c0 + c1 + c2 + c3;
        uint32_t p = s;
        #pragma unroll
        for (int d = 1; d < 64; d <<= 1) {
          uint32_t v = __shfl_up(p, d, 64);
          if (tid >= d) p += v;
        }
        uint32_t e0 = p - s, e1 = e0 + c0, e2 = e1 + c1, e3 = e2 + c2, e4 = e3 + c3;
        uint32_t eb[5] = {e0, e1, e2, e3, e4};
        #pragma unroll
        for (int q = 0; q < 4; ++q)
          if (eb[q] < need && need <= eb[q + 1]) {
            spre = (pre << 8) | (uint32_t)(4 * tid + q);
            sneedS = need - eb[q];
          }
      }
      __syncthreads();
      pre = spre; need = sneedS;
      __syncthreads();
    }
    T1 = pre;
  }

  // validity: exact top-4096 member AND score >= 0.1
  for (int t = tid; t < GCAP; t += NTHR) {
    unsigned long long k = lk[t];
    float v = ord2f(~(uint32_t)(k >> 32));
    bool ok = (k <= T1) && (v >= 0.1f);
    unsigned long long bm = __ballot(ok);
    if (lane == 0) { validm[t >> 6] = bm; accm[t >> 6] = bm; }
  }
  __syncthreads();

  // Jacobi fixpoint of A[i] = V[i] & forall (j->i): !A[j]  (== greedy NMS)
  while (true) {
    __syncthreads();
    if (tid < NMW * 2) supp[tid] = 0;
    if (tid == 0) chg = 0;
    __syncthreads();
    for (uint32_t p = (uint32_t)tid; p < np; p += NTHR) {
      uint32_t pr = pairs[p];
      uint32_t i = pr >> 16, j = pr & 0xffffu;
      if ((accm[i >> 6] >> (i & 63)) & 1ull) atomicOr(&supp[j >> 5], 1u << (j & 31));
    }
    __syncthreads();
    if (tid < NMW) {
      unsigned long long s = ((unsigned long long)supp[2 * tid + 1] << 32) | supp[2 * tid];
      unsigned long long na = validm[tid] & ~s;
      if (na != accm[tid]) { accm[tid] = na; atomicOr(&chg, 1u); }
    }
    __syncthreads();
    if (chg == 0) break;
  }

  // ---- top-KPOST of survivors (radix narrowing) + rank emit ----
  if (tid == 0) {
    uint32_t ns = 0;
    for (int l = 0; l < NMW; ++l) ns += (uint32_t)__builtin_popcountll(accm[l]);
    sneedS = (ns < (uint32_t)KPOST) ? ns : (uint32_t)KPOST;
    orlo = 0; orhi = 0; andlo = ~0u; andhi = ~0u;
  }
  __syncthreads();
  uint32_t need0 = sneedS;
  if (need0 == 0) return;
  {
    unsigned long long myor = 0ull, myand = ~0ull;
    for (int t = tid; t < GCAP; t += NTHR) {
      if ((accm[t >> 6] >> (t & 63)) & 1ull) {
        unsigned long long k = lk[t];
        myor |= k; myand &= k;
      }
    }
    #pragma unroll
    for (int d = 1; d < 64; d <<= 1) { myor |= shflx64(myor, d); myand &= shflx64(myand, d); }
    if (lane == 0) {
      atomicOr(&orlo, (uint32_t)myor); atomicOr(&orhi, (uint32_t)(myor >> 32));
      atomicAnd(&andlo, (uint32_t)myand); atomicAnd(&andhi, (uint32_t)(myand >> 32));
    }
  }
  __syncthreads();
  unsigned long long T2;
  {
    unsigned long long vor = ((unsigned long long)orhi << 32) | orlo;
    unsigned long long vand = ((unsigned long long)andhi << 32) | andlo;
    unsigned long long diff = vor ^ vand;
    unsigned long long pre = 0;
    uint32_t need = need0;
    for (int b = 7; b >= 0; --b) {
      uint32_t db = (uint32_t)(diff >> (8 * b)) & 255u;
      if (db == 0) { pre = (pre << 8) | ((uint32_t)(vand >> (8 * b)) & 255u); continue; }
      if (tid < 256) hsel[tid] = 0;
      __syncthreads();
      for (int t = tid; t < GCAP; t += NTHR) {
        if ((accm[t >> 6] >> (t & 63)) & 1ull) {
          unsigned long long k = lk[t];
          bool pm = (b == 7) ? true : ((k >> (8 * b + 8)) == pre);
          if (pm) atomicAdd(&hsel[(uint32_t)(k >> (8 * b)) & 255u], 1u);
        }
      }
      __syncthreads();
      if (tid < 64) {
        uint32_t c0 = hsel[4 * tid], c1 = hsel[4 * tid + 1],
                 c2 = hsel[4 * tid + 2], c3 = hsel[4 * tid + 3];
        uint32_t s = c0 + c1 + c2 + c3;
        uint32_t p = s;
        #pragma unroll
        for (int d = 1; d < 64; d <<= 1) {
          uint32_t v = __shfl_up(p, d, 64);
          if (tid >= d) p += v;
        }
        uint32_t e0 = p - s, e1 = e0 + c0, e2 = e1 + c1, e3 = e2 + c2, e4 = e3 + c3;
        uint32_t eb[5] = {e0, e1, e2, e3, e4};
        #pragma unroll
        for (int q = 0; q < 4; ++q)
          if (eb[q] < need && need <= eb[q + 1]) {
            spre = (pre << 8) | (uint32_t)(4 * tid + q);
            sneedS = need - eb[q];
          }
      }
      __syncthreads();
      pre = spre; need = sneedS;
      __syncthreads();
    }
    T2 = pre;
  }

  for (int t = tid; t < GCAP; t += NTHR) {
    bool take = ((accm[t >> 6] >> (t & 63)) & 1ull) && (lk[t] <= T2);
    wave_compact32(take, (uint32_t)t, &scnt2, lsel, 512u);
  }
  __syncthreads();
  uint32_t cnt = min(scnt2, 512u);
  if (tid < (int)cnt) kkbuf[tid] = lk[lsel[tid]];
  __syncthreads();
  if (tid < (int)cnt) {
    unsigned long long k0 = kkbuf[tid];
    uint32_t rank = 0;
    #pragma unroll 8
    for (uint32_t p = 0; p < 512u; ++p) rank += (kkbuf[p] < k0) ? 1u : 0u;
    if (rank < (uint32_t)KPOST) {
      int i = (int)lsel[tid];
      out[rank * 6 + 0] = x1a[i];
      out[rank * 6 + 1] = y1a[i];
      out[rank * 6 + 2] = x2a[i];
      out[rank * 6 + 3] = y2a[i];
      out[rank * 6 + 4] = vala[i];
      out[rank * 6 + 5] = (float)laba[i];
    }
  }
}

extern "C" void kernel_launch(void* const* d_in, const int* in_sizes, int n_in,
                              void* d_out, int out_size, void* d_ws, size_t ws_size,
                              hipStream_t stream) {
  const float* boxes = (const float*)d_in[0];
  const float* cls   = (const float*)d_in[1];
  float* out = (float*)d_out;
  char* ws = (char*)d_ws;

  uint32_t* keys = (uint32_t*)(ws + OFF_KEYS);
  unsigned long long* cand = (unsigned long long*)(ws + OFF_CAND);
  uint32_t* pairs = (uint32_t*)(ws + OFF_PAIRS);
  float* x1a = (float*)(ws + OFF_ARR);
  float* y1a = x1a + GCAP;
  float* x2a = y1a + GCAP;
  float* y2a = x2a + GCAP;
  float* vala = y2a + GCAP;
  int* laba = (int*)(vala + GCAP);
  unsigned long long* skg = (unsigned long long*)(laba + GCAP);
  uint8_t* labs = (uint8_t*)(ws + OFF_LAB);
  uint32_t* hist = (uint32_t*)(ws + OFF_ZERO);
  uint32_t* cntc = hist + 768;
  uint32_t* state = cntc + NBLK * CSTR;

  hipMemsetAsync(ws + OFF_ZERO, 0, ZERO_BYTES, stream);
  void* args[] = { (void*)&boxes, (void*)&cls, (void*)&keys, (void*)&labs,
                   (void*)&cand, (void*)&cntc, (void*)&hist, (void*)&state,
                   (void*)&x1a, (void*)&y1a, (void*)&x2a, (void*)&y2a,
                   (void*)&vala, (void*)&laba, (void*)&skg, (void*)&pairs,
                   (void*)&out };
  hipLaunchCooperativeKernel((const void*)k_all, dim3(NBLK), dim3(NTHR), args, 0, stream);
}

// Round 5
// 292.246 us; speedup vs baseline: 1.3079x; 1.2174x over previous
//
#include <hip/hip_runtime.h>
#include <stdint.h>

#define NBOX 2000000
#define NCLS 10
#define KPRE 4096
#define KPOST 500
#define NBLK 256
#define NTHR 1024
#define NWAV (NTHR / 64)
#define SEGC 2048        // cand per-segment cap (avg ~300/segment)
#define GCAP 6144        // gathered candidate cap (>= 4096 + p24-bucket size)
#define NMW  (GCAP / 64) // 96 mask words
#define PCAP 131072      // pair cap
#define LPC  16384       // LDS pair cache (64 KB)
#define CSTR 16          // counter stride in u32 (one 64B line per counter)

// ---- workspace layout (bytes) ----
#define OFF_KEYS  ((size_t)0)                              // NBOX*4
#define OFF_CAND  ((size_t)8000000)                        // NBLK*SEGC*8 = 4 MB
#define OFF_PAIRS (OFF_CAND + (size_t)NBLK * SEGC * 8)     // PCAP*4
#define OFF_ARR   (OFF_PAIRS + (size_t)PCAP * 4)           // 32 B * GCAP
#define OFF_LAB   (OFF_ARR + (size_t)GCAP * 32)            // NBOX u8
#define OFF_ZERO  (OFF_LAB + (size_t)NBOX)                 // hist(768*4) + cnts + state
#define ZERO_BYTES ((size_t)(768 * 4 + NBLK * CSTR * 4 + 64))

__device__ __forceinline__ uint32_t f2ord(float f) {
  uint32_t b = __float_as_uint(f);
  return (b & 0x80000000u) ? ~b : (b | 0x80000000u);
}
__device__ __forceinline__ float ord2f(uint32_t ord) {
  uint32_t b = (ord & 0x80000000u) ? (ord ^ 0x80000000u) : ~ord;
  return __uint_as_float(b);
}

__device__ __forceinline__ unsigned long long shflx64(unsigned long long v, int mask) {
  union { unsigned long long u; int i[2]; } a; a.u = v;
  a.i[0] = __shfl_xor(a.i[0], mask, 64);
  a.i[1] = __shfl_xor(a.i[1], mask, 64);
  return a.u;
}

// lean grid barrier: RELAXED spin (no per-iteration cache maintenance!),
// exactly one release fence before arrive and one acquire fence after exit.
__device__ __forceinline__ void gbar(uint32_t* bar, uint32_t target) {
  __syncthreads();  // drains this block's outstanding writes
  if (threadIdx.x == 0) {
    __threadfence();  // release: L2 writeback once
    __hip_atomic_fetch_add(bar, 1u, __ATOMIC_RELAXED, __HIP_MEMORY_SCOPE_AGENT);
    while (__hip_atomic_load(bar, __ATOMIC_RELAXED, __HIP_MEMORY_SCOPE_AGENT) < target)
      __builtin_amdgcn_s_sleep(8);
    __threadfence();  // acquire: invalidate once after all blocks arrived
  }
  __syncthreads();
}

// full-wave (lanes 0..63): bucket of the need-th smallest in h[256]
__device__ __forceinline__ void wave_bucket(const uint32_t* __restrict__ h, uint32_t need,
                                            uint32_t* bin_out, uint32_t* nd_out) {
  int l = threadIdx.x & 63;
  uint4 h4 = reinterpret_cast<const uint4*>(h)[l];
  uint32_t s = h4.x + h4.y + h4.z + h4.w;
  uint32_t p = s;
  #pragma unroll
  for (int d = 1; d < 64; d <<= 1) {
    uint32_t v = __shfl_up(p, d, 64);
    if (l >= d) p += v;
  }
  uint32_t e0 = p - s, e1 = e0 + h4.x, e2 = e1 + h4.y, e3 = e2 + h4.z, e4 = e3 + h4.w;
  uint32_t eb[5] = {e0, e1, e2, e3, e4};
  uint32_t bin = 0xFFFFFFFFu, nd = 1;
  #pragma unroll
  for (int q = 0; q < 4; ++q)
    if (eb[q] < need && need <= eb[q + 1]) { bin = (uint32_t)(4 * l + q); nd = need - eb[q]; }
  unsigned long long mm = __ballot(bin != 0xFFFFFFFFu);
  int src = mm ? __builtin_ctzll(mm) : 0;
  *bin_out = (uint32_t)__shfl((int)bin, src);
  *nd_out  = (uint32_t)__shfl((int)nd, src);
}

__device__ __forceinline__ void hist_add_wave(uint32_t* lh, uint32_t bin) {
  unsigned long long act = __ballot(1);
  int lane = threadIdx.x & 63;
  unsigned long long rem = act;
  while (rem) {
    int leader = __builtin_ctzll(rem);
    uint32_t lb = __shfl(bin, leader);
    unsigned long long same = __ballot(bin == lb) & act;
    if (lane == leader) atomicAdd(&lh[lb], (uint32_t)__builtin_popcountll(same));
    rem &= ~same;
  }
}

__device__ __forceinline__ void wave_compact(bool take, unsigned long long key,
                                             uint32_t* counter, unsigned long long* buf,
                                             uint32_t cap) {
  unsigned long long mm = __ballot(take);
  if (take) {
    int lane = threadIdx.x & 63;
    unsigned long long lt = (lane == 0) ? 0ull : (~0ull >> (64 - lane));
    int rank = __builtin_popcountll(mm & lt);
    int leader = __builtin_ctzll(mm);
    uint32_t base = 0;
    if (rank == 0) base = atomicAdd(counter, (uint32_t)__builtin_popcountll(mm));
    base = __shfl(base, leader);
    uint32_t pos = base + (uint32_t)rank;
    if (pos < cap) buf[pos] = key;
  }
}

__device__ __forceinline__ void wave_compact32(bool take, uint32_t key,
                                               uint32_t* counter, uint32_t* buf,
                                               uint32_t cap) {
  unsigned long long mm = __ballot(take);
  if (take) {
    int lane = threadIdx.x & 63;
    unsigned long long lt = (lane == 0) ? 0ull : (~0ull >> (64 - lane));
    int rank = __builtin_popcountll(mm & lt);
    int leader = __builtin_ctzll(mm);
    uint32_t base = 0;
    if (rank == 0) base = atomicAdd(counter, (uint32_t)__builtin_popcountll(mm));
    base = __shfl(base, leader);
    uint32_t pos = base + (uint32_t)rank;
    if (pos < cap) buf[pos] = key;
  }
}

// ONE kernel (normal launch; grid=256 blocks <= 256 CUs => co-resident):
// A score | B hist1 | C compact+hist2+sentinels | D p24+selgather | E pairs | F fix(blk0)
__global__ void __launch_bounds__(NTHR) k_all(
    const float* __restrict__ boxes, const float* __restrict__ cls,
    uint32_t* __restrict__ keys, uint8_t* __restrict__ labs,
    unsigned long long* __restrict__ cand, uint32_t* __restrict__ cntc,
    uint32_t* __restrict__ hist, uint32_t* __restrict__ state,
    float* __restrict__ x1a, float* __restrict__ y1a,
    float* __restrict__ x2a, float* __restrict__ y2a,
    float* __restrict__ vala, int* __restrict__ laba,
    unsigned long long* __restrict__ skg, uint32_t* __restrict__ pairs,
    float* __restrict__ out) {
#pragma clang fp contract(off)
  __shared__ unsigned long long lk[GCAP];   // B: sub-hists | D: select list | E: staging | F: keys
  __shared__ uint32_t lpair[LPC];           // F: pair cache (64 KB)
  __shared__ unsigned long long validm[NMW], accm[NMW];
  __shared__ uint32_t lh[256];
  __shared__ uint32_t supp[NMW * 2];
  __shared__ uint32_t hsel[256];
  __shared__ uint32_t lsel[512];
  __shared__ unsigned long long kkbuf[512];
  __shared__ uint32_t sb1, sp16, sp24, dcnt, dbase, chg, scnt2, sneedS;
  __shared__ unsigned long long spre;
  __shared__ uint32_t orlo, orhi, andlo, andhi;

  int tid = threadIdx.x, blk = blockIdx.x;
  int wid = tid >> 6, lane = tid & 63;
  int gtid = blk * NTHR + tid;
  uint32_t* hist0 = hist;
  uint32_t* hist1 = hist + 256;
  uint32_t* hist2 = hist + 512;
  uint32_t* selcnt = state;
  uint32_t* paircnt = state + 1;
  uint32_t* bar = state + 2;
  const int nvec = NBOX / 4;

  // ---- A: score (max over classes) -> ord keys + labels + byte0 hist ----
  for (int i = tid; i < 256; i += NTHR) lh[i] = 0;
  __syncthreads();
  for (int v = gtid; v < nvec; v += NBLK * NTHR) {
    float4 m = reinterpret_cast<const float4*>(cls)[v];
    int lx = 0, ly = 0, lz = 0, lw = 0;
    #pragma unroll
    for (int c = 1; c < NCLS; ++c) {
      float4 x = reinterpret_cast<const float4*>(cls + (size_t)c * NBOX)[v];
      if (x.x > m.x) { m.x = x.x; lx = c; }
      if (x.y > m.y) { m.y = x.y; ly = c; }
      if (x.z > m.z) { m.z = x.z; lz = c; }
      if (x.w > m.w) { m.w = x.w; lw = c; }
    }
    float s[4] = {m.x, m.y, m.z, m.w};
    uint32_t u4[4];
    #pragma unroll
    for (int q = 0; q < 4; ++q) {
      float ms = (s[q] >= 0.1f) ? s[q] : -1.0f;
      uint32_t u = ~f2ord(ms);
      u4[q] = u;
      hist_add_wave(lh, u >> 24);
    }
    reinterpret_cast<uint4*>(keys)[v] = make_uint4(u4[0], u4[1], u4[2], u4[3]);
    uchar4 lb; lb.x = (uint8_t)lx; lb.y = (uint8_t)ly; lb.z = (uint8_t)lz; lb.w = (uint8_t)lw;
    reinterpret_cast<uchar4*>(labs)[v] = lb;
  }
  __syncthreads();
  for (int i = tid; i < 256; i += NTHR) if (lh[i]) atomicAdd(&hist0[i], lh[i]);
  gbar(&bar[0], NBLK);

  // ---- B: hist1 (byte1 | byte0 == b1), per-wave sub-histograms (hot bins!) ----
  if (tid < 64) {
    uint32_t b1, nd1;
    wave_bucket(hist0, KPRE, &b1, &nd1);
    if (tid == 0) sb1 = b1;
  }
  {
    uint32_t* lh16 = (uint32_t*)lk;  // NWAV*256*4 = 16 KB of lk region
    for (int i = tid; i < NWAV * 256; i += NTHR) lh16[i] = 0;
    __syncthreads();
    uint32_t B1 = sb1;
    uint32_t* myh = lh16 + (wid << 8);
    for (int v = gtid; v < nvec; v += NBLK * NTHR) {
      uint4 kv = reinterpret_cast<const uint4*>(keys)[v];
      if ((kv.x >> 24) == B1) atomicAdd(&myh[(kv.x >> 16) & 255u], 1u);
      if ((kv.y >> 24) == B1) atomicAdd(&myh[(kv.y >> 16) & 255u], 1u);
      if ((kv.z >> 24) == B1) atomicAdd(&myh[(kv.z >> 16) & 255u], 1u);
      if ((kv.w >> 24) == B1) atomicAdd(&myh[(kv.w >> 16) & 255u], 1u);
    }
    __syncthreads();
    for (int i = tid; i < 256; i += NTHR) {
      uint32_t s = 0;
      #pragma unroll
      for (int w2 = 0; w2 < NWAV; ++w2) s += lh16[(w2 << 8) | i];
      if (s) atomicAdd(&hist1[i], s);
    }
  }
  gbar(&bar[1], NBLK);

  // ---- C: compact own stripe (top16 <= p16) into own segment + hist2 + sentinels ----
  if (tid < 64) {
    uint32_t b1, nd1, b2, nd2;
    wave_bucket(hist0, KPRE, &b1, &nd1);
    wave_bucket(hist1, nd1, &b2, &nd2);
    if (tid == 0) sp16 = (b1 << 8) | b2;
  }
  for (int i = tid; i < 256; i += NTHR) lh[i] = 0;
  __syncthreads();
  {
    uint32_t p16 = sp16;
    uint32_t* ctr = cntc + blk * CSTR;
    unsigned long long* buf = cand + (size_t)blk * SEGC;
    for (int v = gtid; v < nvec; v += NBLK * NTHR) {
      uint4 kv = reinterpret_cast<const uint4*>(keys)[v];
      uint32_t us[4] = {kv.x, kv.y, kv.z, kv.w};
      #pragma unroll
      for (int q = 0; q < 4; ++q) {
        uint32_t u = us[q];
        uint32_t pref = u >> 16;
        bool take = (pref <= p16);
        unsigned long long key = ((unsigned long long)u << 32) | (uint32_t)(4 * v + q);
        wave_compact(take, key, ctr, buf, SEGC);
        if (take && pref == p16) atomicAdd(&lh[(u >> 8) & 255u], 1u);
      }
    }
    // sentinel-pad gather arrays (D overwrites live slots; barrier separates)
    for (int t = gtid; t < GCAP; t += NBLK * NTHR) {
      x1a[t] = 0.0f; y1a[t] = 0.0f; x2a[t] = 0.0f; y2a[t] = 0.0f;
      vala[t] = -1.0f; laba[t] = 0; skg[t] = ~0ull;
    }
  }
  __syncthreads();
  for (int i = tid; i < 256; i += NTHR) if (lh[i]) atomicAdd(&hist2[i], lh[i]);
  gbar(&bar[2], NBLK);

  // ---- D: p24 + conservative select (whole p24 bucket) + contiguous gather ----
  if (tid < 64) {
    uint32_t b1, nd1, b2, nd2, b3, nd3;
    wave_bucket(hist0, KPRE, &b1, &nd1);
    wave_bucket(hist1, nd1, &b2, &nd2);
    wave_bucket(hist2, nd2, &b3, &nd3);
    if (tid == 0) { sp24 = (b1 << 16) | (b2 << 8) | b3; dcnt = 0; }
  }
  __syncthreads();
  {
    uint32_t p24 = sp24;
    uint32_t n = __hip_atomic_load(cntc + blk * CSTR, __ATOMIC_RELAXED, __HIP_MEMORY_SCOPE_AGENT);
    if (n > SEGC) n = SEGC;
    const unsigned long long* src = cand + (size_t)blk * SEGC;
    unsigned long long* dls = lk;  // LDS reuse as select list
    for (uint32_t i = (uint32_t)tid; i < n; i += NTHR) {
      unsigned long long key = src[i];
      wave_compact((uint32_t)(key >> 40) <= p24, key, &dcnt, dls, (uint32_t)GCAP);
    }
    __syncthreads();
    if (tid == 0) {
      uint32_t c = dcnt; if (c > GCAP) c = GCAP;
      dbase = __hip_atomic_fetch_add(selcnt, c, __ATOMIC_RELAXED, __HIP_MEMORY_SCOPE_AGENT);
      dcnt = c;
    }
    __syncthreads();
    uint32_t c = dcnt, base = dbase;
    for (uint32_t i = (uint32_t)tid; i < c; i += NTHR) {
      unsigned long long key = dls[i];
      uint32_t pos = base + i;
      if (pos < (uint32_t)GCAP) {
        uint32_t idx = (uint32_t)key; if (idx >= NBOX) idx = 0;
        uint32_t u = (uint32_t)(key >> 32);
        x1a[pos] = boxes[idx];
        y1a[pos] = boxes[(size_t)NBOX + idx];
        x2a[pos] = boxes[(size_t)2 * NBOX + idx];
        y2a[pos] = boxes[(size_t)3 * NBOX + idx];
        vala[pos] = ord2f(~u);
        laba[pos] = (int)labs[idx];
        skg[pos] = key;
      }
    }
  }
  gbar(&bar[3], NBLK);

  // ---- E: suppression pairs over dynamic triangular 64x64 tiles ----
  {
    uint32_t gc = __hip_atomic_load(selcnt, __ATOMIC_RELAXED, __HIP_MEMORY_SCOPE_AGENT);
    if (gc > (uint32_t)GCAP) gc = (uint32_t)GCAP;
    int rows = (int)((gc + 63) >> 6);
    int NT = rows * (rows + 1) / 2;
    float* psx1 = (float*)lk;  // staging carved from lk region (28 KB < 48 KB)
    float* psy1 = psx1 + NWAV * 64;
    float* psx2 = psy1 + NWAV * 64;
    float* psy2 = psx2 + NWAV * 64;
    float* psar = psy2 + NWAV * 64;
    unsigned long long* psk = (unsigned long long*)(psar + NWAV * 64);
    int W = blk * NWAV + wid;
    int wb = wid << 6;
    for (int T = W; T < NT; T += NBLK * NWAV) {
      float Rf = (float)rows;
      float disc = (2.0f * Rf + 1.0f) * (2.0f * Rf + 1.0f) - 8.0f * (float)T;
      disc = disc > 0.0f ? disc : 0.0f;
      int by = (int)(((2.0f * Rf + 1.0f) - sqrtf(disc)) * 0.5f);
      if (by < 0) by = 0;
      if (by > rows - 1) by = rows - 1;
      while (by > 0 && T < by * rows - (by * (by - 1)) / 2) --by;
      while (by < rows - 1 && T >= (by + 1) * rows - ((by + 1) * by) / 2) ++by;
      int cum = by * rows - (by * (by - 1)) / 2;
      int bx = by + (T - cum);
      int i = by * 64 + lane;
      int j0 = bx * 64 + lane;
      float cx1 = x1a[j0], cy1 = y1a[j0], cx2 = x2a[j0], cy2 = y2a[j0];
      psx1[wb + lane] = cx1; psy1[wb + lane] = cy1;
      psx2[wb + lane] = cx2; psy2[wb + lane] = cy2;
      psar[wb + lane] = fmaxf(cx2 - cx1, 0.0f) * fmaxf(cy2 - cy1, 0.0f);
      psk[wb + lane] = skg[j0];
      float x1i = x1a[i], y1i = y1a[i], x2i = x2a[i], y2i = y2a[i];
      unsigned long long rk = skg[i];
      float ari = fmaxf(x2i - x1i, 0.0f) * fmaxf(y2i - y1i, 0.0f);
      unsigned long long w = 0ull;
      #pragma unroll 8
      for (int jj = 0; jj < 64; ++jj) {
        int j = bx * 64 + jj;
        float iw = fmaxf(fminf(x2i, psx2[wb + jj]) - fmaxf(x1i, psx1[wb + jj]), 0.0f);
        float ih = fmaxf(fminf(y2i, psy2[wb + jj]) - fmaxf(y1i, psy1[wb + jj]), 0.0f);
        float inter = iw * ih;
        float den = ((ari + psar[wb + jj]) - inter) + 1e-8f;  // exact ref op order
        float iou = inter / den;
        if ((iou > 0.5f) && (j > i)) w |= (1ull << jj);
      }
      while (__ballot(w != 0ull)) {
        bool tk = (w != 0ull);
        uint32_t pr = 0;
        if (tk) {
          int b = __builtin_ctzll(w); w &= w - 1;
          int j = bx * 64 + b;
          bool i_sup = (rk < psk[wb + b]);  // smaller key suppresses
          pr = i_sup ? (((uint32_t)i << 16) | (uint32_t)j)
                     : (((uint32_t)j << 16) | (uint32_t)i);
        }
        wave_compact32(tk, pr, paircnt, pairs, (uint32_t)PCAP);
      }
    }
  }
  gbar(&bar[4], NBLK);
  if (blk != 0) return;

  // ---- F (block 0): exact top-4096 cut + Jacobi fixpoint + top-500 emit ----
  uint32_t gc = __hip_atomic_load(selcnt, __ATOMIC_RELAXED, __HIP_MEMORY_SCOPE_AGENT);
  if (gc > (uint32_t)GCAP) gc = (uint32_t)GCAP;
  uint32_t np = __hip_atomic_load(paircnt, __ATOMIC_RELAXED, __HIP_MEMORY_SCOPE_AGENT);
  if (np > (uint32_t)PCAP) np = (uint32_t)PCAP;
  for (int t = tid; t < KPOST * 6; t += NTHR) out[t] = 0.0f;
  if (tid < 512) kkbuf[tid] = ~0ull;
  for (int t = tid; t < GCAP; t += NTHR) lk[t] = (t < (int)gc) ? skg[t] : ~0ull;
  bool plds = (np <= (uint32_t)LPC);
  if (plds) for (uint32_t p = (uint32_t)tid; p < np; p += NTHR) lpair[p] = pairs[p];
  if (tid == 0) { orlo = 0; orhi = 0; andlo = ~0u; andhi = ~0u; scnt2 = 0; }
  __syncthreads();

  // radix #1: T1 = exact need1-th smallest key among gathered
  uint32_t need1 = (gc < (uint32_t)KPRE) ? gc : (uint32_t)KPRE;
  if (need1 == 0) return;
  {
    unsigned long long myor = 0ull, myand = ~0ull;
    for (int t = tid; t < (int)gc; t += NTHR) {
      unsigned long long k = lk[t];
      myor |= k; myand &= k;
    }
    #pragma unroll
    for (int d = 1; d < 64; d <<= 1) { myor |= shflx64(myor, d); myand &= shflx64(myand, d); }
    if (lane == 0) {
      atomicOr(&orlo, (uint32_t)myor); atomicOr(&orhi, (uint32_t)(myor >> 32));
      atomicAnd(&andlo, (uint32_t)myand); atomicAnd(&andhi, (uint32_t)(myand >> 32));
    }
  }
  __syncthreads();
  unsigned long long T1;
  {
    unsigned long long vor = ((unsigned long long)orhi << 32) | orlo;
    unsigned long long vand = ((unsigned long long)andhi << 32) | andlo;
    unsigned long long diff = vor ^ vand;
    unsigned long long pre = 0;
    uint32_t need = need1;
    for (int b = 7; b >= 0; --b) {
      uint32_t db = (uint32_t)(diff >> (8 * b)) & 255u;
      if (db == 0) { pre = (pre << 8) | ((uint32_t)(vand >> (8 * b)) & 255u); continue; }
      if (tid < 256) hsel[tid] = 0;
      __syncthreads();
      for (int t = tid; t < (int)gc; t += NTHR) {
        unsigned long long k = lk[t];
        bool pm = (b == 7) ? true : ((k >> (8 * b + 8)) == pre);
        if (pm) atomicAdd(&hsel[(uint32_t)(k >> (8 * b)) & 255u], 1u);
      }
      __syncthreads();
      if (tid < 64) {
        uint32_t c0 = hsel[4 * tid], c1 = hsel[4 * tid + 1],
                 c2 = hsel[4 * tid + 2], c3 = hsel[4 * tid + 3];
        uint32_t s = c0 + c1 + c2 + c3;
        uint32_t p = s;
        #pragma unroll
        for (int d = 1; d < 64; d <<= 1) {
          uint32_t v = __shfl_up(p, d, 64);
          if (tid >= d) p += v;
        }
        uint32_t e0 = p - s, e1 = e0 + c0, e2 = e1 + c1, e3 = e2 + c2, e4 = e3 + c3;
        uint32_t eb[5] = {e0, e1, e2, e3, e4};
        #pragma unroll
        for (int q = 0; q < 4; ++q)
          if (eb[q] < need && need <= eb[q + 1]) {
            spre = (pre << 8) | (uint32_t)(4 * tid + q);
            sneedS = need - eb[q];
          }
      }
      __syncthreads();
      pre = spre; need = sneedS;
      __syncthreads();
    }
    T1 = pre;
  }

  // validity: exact top-4096 member AND score >= 0.1
  for (int t = tid; t < GCAP; t += NTHR) {
    unsigned long long k = lk[t];
    float v = ord2f(~(uint32_t)(k >> 32));
    bool ok = (k <= T1) && (v >= 0.1f);
    unsigned long long bm = __ballot(ok);
    if (lane == 0) { validm[t >> 6] = bm; accm[t >> 6] = bm; }
  }
  __syncthreads();

  // Jacobi fixpoint of A[i] = V[i] & forall (j->i): !A[j]  (== greedy NMS)
  while (true) {
    __syncthreads();
    if (tid < NMW * 2) supp[tid] = 0;
    if (tid == 0) chg = 0;
    __syncthreads();
    if (plds) {
      for (uint32_t p = (uint32_t)tid; p < np; p += NTHR) {
        uint32_t pr = lpair[p];
        uint32_t i = pr >> 16, j = pr & 0xffffu;
        if ((accm[i >> 6] >> (i & 63)) & 1ull) atomicOr(&supp[j >> 5], 1u << (j & 31));
      }
    } else {
      for (uint32_t p = (uint32_t)tid; p < np; p += NTHR) {
        uint32_t pr = pairs[p];
        uint32_t i = pr >> 16, j = pr & 0xffffu;
        if ((accm[i >> 6] >> (i & 63)) & 1ull) atomicOr(&supp[j >> 5], 1u << (j & 31));
      }
    }
    __syncthreads();
    if (tid < NMW) {
      unsigned long long s = ((unsigned long long)supp[2 * tid + 1] << 32) | supp[2 * tid];
      unsigned long long na = validm[tid] & ~s;
      if (na != accm[tid]) { accm[tid] = na; atomicOr(&chg, 1u); }
    }
    __syncthreads();
    if (chg == 0) break;
  }

  // ---- top-KPOST of survivors (radix narrowing) + rank emit ----
  if (tid == 0) {
    uint32_t ns = 0;
    for (int l = 0; l < NMW; ++l) ns += (uint32_t)__builtin_popcountll(accm[l]);
    sneedS = (ns < (uint32_t)KPOST) ? ns : (uint32_t)KPOST;
    orlo = 0; orhi = 0; andlo = ~0u; andhi = ~0u;
  }
  __syncthreads();
  uint32_t need0 = sneedS;
  if (need0 == 0) return;
  {
    unsigned long long myor = 0ull, myand = ~0ull;
    for (int t = tid; t < GCAP; t += NTHR) {
      if ((accm[t >> 6] >> (t & 63)) & 1ull) {
        unsigned long long k = lk[t];
        myor |= k; myand &= k;
      }
    }
    #pragma unroll
    for (int d = 1; d < 64; d <<= 1) { myor |= shflx64(myor, d); myand &= shflx64(myand, d); }
    if (lane == 0) {
      atomicOr(&orlo, (uint32_t)myor); atomicOr(&orhi, (uint32_t)(myor >> 32));
      atomicAnd(&andlo, (uint32_t)myand); atomicAnd(&andhi, (uint32_t)(myand >> 32));
    }
  }
  __syncthreads();
  unsigned long long T2;
  {
    unsigned long long vor = ((unsigned long long)orhi << 32) | orlo;
    unsigned long long vand = ((unsigned long long)andhi << 32) | andlo;
    unsigned long long diff = vor ^ vand;
    unsigned long long pre = 0;
    uint32_t need = need0;
    for (int b = 7; b >= 0; --b) {
      uint32_t db = (uint32_t)(diff >> (8 * b)) & 255u;
      if (db == 0) { pre = (pre << 8) | ((uint32_t)(vand >> (8 * b)) & 255u); continue; }
      if (tid < 256) hsel[tid] = 0;
      __syncthreads();
      for (int t = tid; t < GCAP; t += NTHR) {
        if ((accm[t >> 6] >> (t & 63)) & 1ull) {
          unsigned long long k = lk[t];
          bool pm = (b == 7) ? true : ((k >> (8 * b + 8)) == pre);
          if (pm) atomicAdd(&hsel[(uint32_t)(k >> (8 * b)) & 255u], 1u);
        }
      }
      __syncthreads();
      if (tid < 64) {
        uint32_t c0 = hsel[4 * tid], c1 = hsel[4 * tid + 1],
                 c2 = hsel[4 * tid + 2], c3 = hsel[4 * tid + 3];
        uint32_t s = c0 + c1 + c2 + c3;
        uint32_t p = s;
        #pragma unroll
        for (int d = 1; d < 64; d <<= 1) {
          uint32_t v = __shfl_up(p, d, 64);
          if (tid >= d) p += v;
        }
        uint32_t e0 = p - s, e1 = e0 + c0, e2 = e1 + c1, e3 = e2 + c2, e4 = e3 + c3;
        uint32_t eb[5] = {e0, e1, e2, e3, e4};
        #pragma unroll
        for (int q = 0; q < 4; ++q)
          if (eb[q] < need && need <= eb[q + 1]) {
            spre = (pre << 8) | (uint32_t)(4 * tid + q);
            sneedS = need - eb[q];
          }
      }
      __syncthreads();
      pre = spre; need = sneedS;
      __syncthreads();
    }
    T2 = pre;
  }

  for (int t = tid; t < GCAP; t += NTHR) {
    bool take = ((accm[t >> 6] >> (t & 63)) & 1ull) && (lk[t] <= T2);
    wave_compact32(take, (uint32_t)t, &scnt2, lsel, 512u);
  }
  __syncthreads();
  uint32_t cnt = min(scnt2, 512u);
  if (tid < (int)cnt) kkbuf[tid] = lk[lsel[tid]];
  __syncthreads();
  if (tid < (int)cnt) {
    unsigned long long k0 = kkbuf[tid];
    uint32_t rank = 0;
    #pragma unroll 8
    for (uint32_t p = 0; p < 512u; ++p) rank += (kkbuf[p] < k0) ? 1u : 0u;
    if (rank < (uint32_t)KPOST) {
      int i = (int)lsel[tid];
      out[rank * 6 + 0] = x1a[i];
      out[rank * 6 + 1] = y1a[i];
      out[rank * 6 + 2] = x2a[i];
      out[rank * 6 + 3] = y2a[i];
      out[rank * 6 + 4] = vala[i];
      out[rank * 6 + 5] = (float)laba[i];
    }
  }
}

extern "C" void kernel_launch(void* const* d_in, const int* in_sizes, int n_in,
                              void* d_out, int out_size, void* d_ws, size_t ws_size,
                              hipStream_t stream) {
  const float* boxes = (const float*)d_in[0];
  const float* cls   = (const float*)d_in[1];
  float* out = (float*)d_out;
  char* ws = (char*)d_ws;

  uint32_t* keys = (uint32_t*)(ws + OFF_KEYS);
  unsigned long long* cand = (unsigned long long*)(ws + OFF_CAND);
  uint32_t* pairs = (uint32_t*)(ws + OFF_PAIRS);
  float* x1a = (float*)(ws + OFF_ARR);
  float* y1a = x1a + GCAP;
  float* x2a = y1a + GCAP;
  float* y2a = x2a + GCAP;
  float* vala = y2a + GCAP;
  int* laba = (int*)(vala + GCAP);
  unsigned long long* skg = (unsigned long long*)(laba + GCAP);
  uint8_t* labs = (uint8_t*)(ws + OFF_LAB);
  uint32_t* hist = (uint32_t*)(ws + OFF_ZERO);
  uint32_t* cntc = hist + 768;
  uint32_t* state = cntc + NBLK * CSTR;

  hipMemsetAsync(ws + OFF_ZERO, 0, ZERO_BYTES, stream);
  // Normal (graph-capturable) launch: grid=256 blocks, 1 per CU => co-resident by capacity.
  k_all<<<dim3(NBLK), dim3(NTHR), 0, stream>>>(
      boxes, cls, keys, labs, cand, cntc, hist, state,
      x1a, y1a, x2a, y2a, vala, laba, skg, pairs, out);
}